// Round 8
// baseline (3161.227 us; speedup 1.0000x reference)
//
#include <hip/hip_runtime.h>

typedef _Float16 half8 __attribute__((ext_vector_type(8)));
typedef float f32x4 __attribute__((ext_vector_type(4)));
typedef unsigned uint32x4 __attribute__((ext_vector_type(4)));
typedef unsigned long long u64;

#define MFMA16(a,b,c) __builtin_amdgcn_mfma_f32_16x16x32_f16((a),(b),(c),0,0,0)

constexpr int B_SZ = 128, S_LEN = 512, I_SZ = 512, H_SZ = 1024, O_SZ = 512;

// workspace layout (bytes)
constexpr size_t XW_OFF   = 0;                                            // f16 [S][B][H] (128 MB)
constexpr size_t X16_OFF  = XW_OFF   + (size_t)S_LEN * B_SZ * H_SZ * 2;   // f16 [B*S][I] (64 MB)
constexpr size_t WXHT_OFF = X16_OFF  + (size_t)B_SZ * S_LEN * I_SZ * 2;   // f16 [H][I]
constexpr size_t WHHT_OFF = WXHT_OFF + (size_t)H_SZ * I_SZ * 2;           // f16 [H][H]
constexpr size_t WYHT_OFF = WHHT_OFF + (size_t)H_SZ * H_SZ * 2;           // f16 [O][H]
constexpr size_t HB_OFF   = WYHT_OFF + (size_t)O_SZ * H_SZ * 2;           // u64 [8][2][16][512] (1 MB)

// epoch-exchange geometry (u64 units)
constexpr size_t HB_ROW   = 512;                  // 1024 f16 cols, 2 per u64
constexpr size_t HB_PAR   = 16 * HB_ROW;          // 8192
constexpr size_t HB_GRP   = 2 * HB_PAR;           // 16384

// ---------------- agent-scope (L3 coherence point) helpers — round-2/6 proven ----------------
__device__ __forceinline__ u64 ag_load64(const u64* p) {
  return __hip_atomic_load(p, __ATOMIC_RELAXED, __HIP_MEMORY_SCOPE_AGENT);
}
__device__ __forceinline__ void ag_store64(u64* p, u64 v) {
  __hip_atomic_store(p, v, __ATOMIC_RELAXED, __HIP_MEMORY_SCOPE_AGENT);
}

__device__ __forceinline__ float ftanh(float z) {
  // tanh(z) = 1 - 2/(e^{2z}+1); e^{2z} = 2^(2*log2e*z). Limits: +inf->1, -inf->-1.
  float e = __builtin_amdgcn_exp2f(z * 2.8853900817779268f);
  return fmaf(-2.f, __builtin_amdgcn_rcpf(e + 1.f), 1.f);
}

// ---------------- prep kernels (proven) ----------------
__global__ void k_cvt_x(const float* __restrict__ in, _Float16* __restrict__ out) {
  size_t i = ((size_t)blockIdx.x * 256 + threadIdx.x) * 8;
  float4 a = *(const float4*)(in + i);
  float4 b = *(const float4*)(in + i + 4);
  half8 h;
  h[0] = (_Float16)a.x; h[1] = (_Float16)a.y; h[2] = (_Float16)a.z; h[3] = (_Float16)a.w;
  h[4] = (_Float16)b.x; h[5] = (_Float16)b.y; h[6] = (_Float16)b.z; h[7] = (_Float16)b.w;
  *(half8*)(out + i) = h;
}

__global__ void k_transpose_cvt(const float* __restrict__ in, _Float16* __restrict__ out,
                                int K, int N) {
  int k = blockIdx.x * 256 + threadIdx.x;
  int n = blockIdx.y;
  out[(size_t)n * K + k] = (_Float16)in[(size_t)k * N + n];
}

// ---------------- phase 1: xW = x @ W_xh + b -> f16 [S][B][H] (proven) ----------------
__launch_bounds__(256, 1)
__global__ void k_xw_gemm(const _Float16* __restrict__ A,   // [65536][512]
                          const _Float16* __restrict__ BT,  // [1024][512]
                          const float* __restrict__ bias,   // [1024]
                          _Float16* __restrict__ xw)        // [S][B][H]
{
  const int m0 = blockIdx.y * 128;
  const int n0 = blockIdx.x * 128;
  __shared__ __align__(16) _Float16 la[128][72];
  __shared__ __align__(16) _Float16 lb[128][72];
  const int tid = threadIdx.x;
  const int w = tid >> 6, l = tid & 63;
  const int wr = w >> 1, wc = w & 1;
  const int cl = l & 15;
  const int kh = (l >> 4) << 3;
  const int rl = (l >> 4) << 2;

  f32x4 acc[4][4] = {};

  for (int kb = 0; kb < 512; kb += 64) {
    {
      const int r = tid >> 1, sg = tid & 1;
      const _Float16* ga = A  + (size_t)(m0 + r) * 512 + kb + sg * 32;
      const _Float16* gb = BT + (size_t)(n0 + r) * 512 + kb + sg * 32;
      _Float16* da = &la[r][sg * 32];
      _Float16* db = &lb[r][sg * 32];
      #pragma unroll
      for (int i = 0; i < 4; i++) *(half8*)(da + i * 8) = *(const half8*)(ga + i * 8);
      #pragma unroll
      for (int i = 0; i < 4; i++) *(half8*)(db + i * 8) = *(const half8*)(gb + i * 8);
    }
    __syncthreads();
    #pragma unroll
    for (int kk = 0; kk < 64; kk += 32) {
      half8 af[4], bf[4];
      #pragma unroll
      for (int mi = 0; mi < 4; mi++) af[mi] = *(const half8*)(&la[wr * 64 + mi * 16 + cl][kk + kh]);
      #pragma unroll
      for (int ni = 0; ni < 4; ni++) bf[ni] = *(const half8*)(&lb[wc * 64 + ni * 16 + cl][kk + kh]);
      #pragma unroll
      for (int mi = 0; mi < 4; mi++)
        #pragma unroll
        for (int ni = 0; ni < 4; ni++)
          acc[mi][ni] = MFMA16(af[mi], bf[ni], acc[mi][ni]);
    }
    __syncthreads();
  }

  #pragma unroll
  for (int mi = 0; mi < 4; mi++)
    #pragma unroll
    for (int ni = 0; ni < 4; ni++) {
      const int col = n0 + wc * 64 + ni * 16 + cl;
      const float bv = bias[col];
      #pragma unroll
      for (int r = 0; r < 4; r++) {
        const int m = m0 + wr * 64 + mi * 16 + rl + r;
        const int b = m >> 9;        // A rows are (b, s), S=512
        const int s = m & 511;
        xw[((size_t)(s * B_SZ + b) << 10) + col] = (_Float16)(acc[mi][ni][r] + bv);
      }
    }
}

// ---------------- phase 2+3: persistent recurrence, epoch-embedded exchange ----------------
// 8 groups (g=bid&7, 16 batch rows) x 32 wgs (j=bid>>3, 32 H-cols), ONE wave each.
// Exchange word: u64 = { hi32 = 2 packed f16 (cols c,c+1), lo32 = epoch (= step) },
// written by ONE atomic agent store -> epoch validates its own payload (no
// store-ordering race possible). Consumers poll lo32 == t and feed hi32 straight
// into MFMA A fragments. No tags, no drains, no barriers.
// Geometry (u64): row stride 512 (1024 cols / 2), parity 8192, group 16384.
//   producer wg j, lane l: row=l>>2, u64 j*16 + (l&3)*4 + k   (k=0..3) — disjoint.
//   consumer lane l: row=cl=l&15, u64 p*16 + (l>>4)*4 + k, p=0..31 — max 511 ✓.
// WAR (2 parity buffers): producer stores h_{t+1} only after observing ALL of
// h_t; observing epoch-t from wg B implies B finished reading h_{t-1}; so
// overwriting h_{t-1}'s parity buffer is safe.
// Replay-ABA: stale epochs (prior replay) collide only at t=511/512 where the
// stale payload is bit-identical (deterministic trajectory) -> still correct;
// poison 0xAAAAAAAA never equals epochs 1..512 -> no memset needed.
// Polls are retry-bounded: a protocol bug yields a wrong answer, never a hang.

template<int BLK0>
__device__ __forceinline__ void issueq(u64 (&buf)[8][4], const u64* hrow) {
  #pragma unroll
  for (int b = 0; b < 8; b++)
    #pragma unroll
    for (int k = 0; k < 4; k++)
      buf[b][k] = ag_load64(hrow + ((BLK0 + b) << 4) + k);
}

template<int BLK0>
__device__ __forceinline__ unsigned epbad(const u64 (&buf)[8][4], unsigned ep) {
  unsigned bad = 0;
  #pragma unroll
  for (int b = 0; b < 8; b++)
    #pragma unroll
    for (int k = 0; k < 4; k++)
      bad |= ((unsigned)buf[b][k]) ^ ep;
  return bad;
}

template<int BLK0>
__device__ __forceinline__ void checkq(u64 (&buf)[8][4], const u64* hrow, unsigned ep) {
  unsigned bad = epbad<BLK0>(buf, ep);
  for (int it = 0; bad && it < (1 << 12); ++it) {
    __builtin_amdgcn_s_sleep(1);
    issueq<BLK0>(buf, hrow);
    bad = epbad<BLK0>(buf, ep);
  }
}

template<int BLK0>
__device__ __forceinline__ void pollq(u64 (&buf)[8][4], const u64* hrow, unsigned ep) {
  issueq<BLK0>(buf, hrow);
  checkq<BLK0>(buf, hrow, ep);
}

template<int BLK0>
__device__ __forceinline__ void mfmaq(const u64 (&buf)[8][4],
                                      const _Float16 (*lw)[1032],
                                      int cl, int kh, f32x4 (&acc)[2][2]) {
  #pragma unroll
  for (int b = 0; b < 8; b++) {
    uint32x4 u;
    #pragma unroll
    for (int k = 0; k < 4; k++) u[k] = (unsigned)(buf[b][k] >> 32);
    half8 a = __builtin_bit_cast(half8, u);
    const int p = BLK0 + b;
    half8 w0 = *(const half8*)&lw[cl][(p << 5) + kh];
    half8 w1 = *(const half8*)&lw[16 + cl][(p << 5) + kh];
    acc[0][p & 1] = MFMA16(a, w0, acc[0][p & 1]);
    acc[1][p & 1] = MFMA16(a, w1, acc[1][p & 1]);
  }
}

template<int BLK0>
__device__ __forceinline__ void mfmaq_o(const u64 (&buf)[8][4],
                                        const _Float16* bsrc,
                                        int kh, f32x4 (&oa)[2]) {
  #pragma unroll
  for (int b = 0; b < 8; b++) {
    uint32x4 u;
    #pragma unroll
    for (int k = 0; k < 4; k++) u[k] = (unsigned)(buf[b][k] >> 32);
    half8 a = __builtin_bit_cast(half8, u);
    const int p = BLK0 + b;
    half8 wv = *(const half8*)(bsrc + (p << 5) + kh);
    oa[p & 1] = MFMA16(a, wv, oa[p & 1]);
  }
}

__launch_bounds__(64, 1)
__global__ void k_rnn(const _Float16* __restrict__ xw,    // [S][B][H]
                      const _Float16* __restrict__ WhhT,  // [H][H]
                      const _Float16* __restrict__ WyhT,  // [O][H]
                      const float* __restrict__ Wby,
                      u64* __restrict__ hb,               // [8][2][16][512]
                      float* __restrict__ out)            // [B][O]
{
  __shared__ __align__(16) _Float16 lw[32][1032];  // W_hh^T slice (2064B rows)
  __shared__ __align__(16) _Float16 stb[16][40];   // repack bounce (80B rows, 16B-aligned)

  const int bid = blockIdx.x;
  const int g = bid & 7, j = bid >> 3;
  const int l = threadIdx.x;            // 0..63
  const int cl  = l & 15;
  const int kh  = (l >> 4) << 3;        // f16 col offset within a 32-col k-block
  const int kh4 = (l >> 4) << 2;        // same in u64 (col-pair) units
  const int rl  = (l >> 4) << 2;
  const int r0  = g << 4;
  const int n0  = j << 5;
  u64* hbg = hb + (size_t)g * HB_GRP;

  // load W_hh^T rows n0..n0+31 into LDS (64 KB, once; single wave -> no barrier)
  for (int i = l; i < 32 * 128; i += 64) {
    const int row = i >> 7, c8 = (i & 127) << 3;
    *(half8*)&lw[row][c8] = *(const half8*)&WhhT[((size_t)(n0 + row) << 10) + c8];
  }

  for (int t = 0; t < 512; t++) {
    // xw_t addend for this wg's 16x32 block (plain loads; consumed after MFMA)
    float xv[2][4];
    {
      const _Float16* p = xw + ((size_t)(t * 128 + r0 + rl) << 10) + n0 + cl;
      #pragma unroll
      for (int f = 0; f < 2; f++)
        #pragma unroll
        for (int r = 0; r < 4; r++)
          xv[f][r] = (float)p[((size_t)r << 10) + (f << 4)];
    }

    f32x4 acc[2][2] = {{{}, {}}, {{}, {}}};
    if (t > 0) {
      const unsigned ep = (unsigned)t;
      const u64* hrow = hbg + (size_t)(t & 1) * HB_PAR + (size_t)cl * HB_ROW + kh4;
      u64 qa[8][4], qb[8][4];
      pollq<0>(qa, hrow, ep);                 // quarter 0 (blocks 0-7), retry until fresh
      issueq<8>(qb, hrow);                    // overlap quarter 1 loads with Q0 MFMA
      mfmaq<0>(qa, lw, cl, kh, acc);
      checkq<8>(qb, hrow, ep);
      issueq<16>(qa, hrow);
      mfmaq<8>(qb, lw, cl, kh, acc);
      checkq<16>(qa, hrow, ep);
      issueq<24>(qb, hrow);
      mfmaq<16>(qa, lw, cl, kh, acc);
      checkq<24>(qb, hrow, ep);
      mfmaq<24>(qb, lw, cl, kh, acc);
    }

    // h_{t+1} = tanh(xw_t + h_t @ W_hh): wave-local bounce, epoch-packed publish
    #pragma unroll
    for (int f = 0; f < 2; f++)
      #pragma unroll
      for (int r = 0; r < 4; r++) {
        float z = xv[f][r] + acc[f][0][r] + acc[f][1][r];
        stb[rl + r][(f << 4) + cl] = (_Float16)ftanh(z);
      }
    asm volatile("s_waitcnt lgkmcnt(0)" ::: "memory");   // wave-local LDS RAW
    __builtin_amdgcn_sched_barrier(0);
    {
      const int row = l >> 2, c4 = (l & 3) << 2;          // 4 u64 (8 f16 cols) per lane
      const unsigned* sp = (const unsigned*)&stb[row][(l & 3) << 3];
      unsigned d[4];
      #pragma unroll
      for (int k = 0; k < 4; k++) d[k] = sp[k];
      u64* dst = hbg + (size_t)((t + 1) & 1) * HB_PAR + (size_t)row * HB_ROW + (j << 4) + c4;
      const u64 epn = (u64)(unsigned)(t + 1);
      #pragma unroll
      for (int k = 0; k < 4; k++)
        ag_store64(dst + k, ((u64)d[k] << 32) | epn);
    }
    // no drain, no tag: each word self-validates via its embedded epoch
  }

  // ---------- phase 3: out = h_512 @ W_yh + b_y (h_512 in parity-0, epoch 512) ----------
  {
    const unsigned ep = 512u;
    const u64* hrow = hbg + (size_t)cl * HB_ROW + kh4;
    const int oc = (j << 4) + cl;                 // 32 wgs x 16 cols = 512
    const _Float16* bsrc = WyhT + ((size_t)oc << 10);
    f32x4 oa[2] = {{}, {}};
    u64 qa[8][4], qb[8][4];
    pollq<0>(qa, hrow, ep);
    issueq<8>(qb, hrow);
    mfmaq_o<0>(qa, bsrc, kh, oa);
    checkq<8>(qb, hrow, ep);
    issueq<16>(qa, hrow);
    mfmaq_o<8>(qb, bsrc, kh, oa);
    checkq<16>(qa, hrow, ep);
    issueq<24>(qb, hrow);
    mfmaq_o<16>(qa, bsrc, kh, oa);
    checkq<24>(qb, hrow, ep);
    mfmaq_o<24>(qb, bsrc, kh, oa);

    const float bb = Wby[oc];
    #pragma unroll
    for (int r = 0; r < 4; r++)
      out[((size_t)(r0 + rl + r) << 9) + oc] = oa[0][r] + oa[1][r] + bb;
  }
}

// ---------------- host ----------------
extern "C" void kernel_launch(void* const* d_in, const int* in_sizes, int n_in,
                              void* d_out, int out_size, void* d_ws, size_t ws_size,
                              hipStream_t stream) {
  const float* x   = (const float*)d_in[0];
  const float* Wxh = (const float*)d_in[1];
  const float* Whh = (const float*)d_in[2];
  const float* Wyh = (const float*)d_in[3];
  const float* Wbh = (const float*)d_in[4];
  const float* Wby = (const float*)d_in[5];
  float* out = (float*)d_out;

  char* ws = (char*)d_ws;
  _Float16* xw   = (_Float16*)(ws + XW_OFF);
  _Float16* x16  = (_Float16*)(ws + X16_OFF);
  _Float16* WxhT = (_Float16*)(ws + WXHT_OFF);
  _Float16* WhhT = (_Float16*)(ws + WHHT_OFF);
  _Float16* WyhT = (_Float16*)(ws + WYHT_OFF);
  u64*      hb   = (u64*)(ws + HB_OFF);

  k_cvt_x<<<16384, 256, 0, stream>>>(x, x16);
  k_transpose_cvt<<<dim3(2, 1024), 256, 0, stream>>>(Wxh, WxhT, 512, 1024);
  k_transpose_cvt<<<dim3(4, 1024), 256, 0, stream>>>(Whh, WhhT, 1024, 1024);
  k_transpose_cvt<<<dim3(4, 512),  256, 0, stream>>>(Wyh, WyhT, 1024, 512);

  k_xw_gemm<<<dim3(8, 512), 256, 0, stream>>>(x16, WxhT, Wbh, xw);

  k_rnn<<<256, 64, 0, stream>>>(xw, WhhT, WyhT, Wby, hb, out);
}

// Round 9
// 1977.202 us; speedup vs baseline: 1.5988x; 1.5988x over previous
//
#include <hip/hip_runtime.h>

typedef _Float16 half8 __attribute__((ext_vector_type(8)));
typedef float f32x4 __attribute__((ext_vector_type(4)));
typedef unsigned long long u64;
typedef u64 u64x2 __attribute__((ext_vector_type(2)));

#define MFMA16(a,b,c) __builtin_amdgcn_mfma_f32_16x16x32_f16((a),(b),(c),0,0,0)

constexpr int B_SZ = 128, S_LEN = 512, I_SZ = 512, H_SZ = 1024, O_SZ = 512;

// workspace layout (bytes)
constexpr size_t XW_OFF   = 0;                                            // f16 [S][B][H] (128 MB)
constexpr size_t X16_OFF  = XW_OFF   + (size_t)S_LEN * B_SZ * H_SZ * 2;   // f16 [B*S][I] (64 MB)
constexpr size_t WXHT_OFF = X16_OFF  + (size_t)B_SZ * S_LEN * I_SZ * 2;   // f16 [H][I]
constexpr size_t WHHT_OFF = WXHT_OFF + (size_t)H_SZ * I_SZ * 2;           // f16 [H][H]
constexpr size_t WYHT_OFF = WHHT_OFF + (size_t)H_SZ * H_SZ * 2;           // f16 [O][H]
constexpr size_t HB_OFF   = WYHT_OFF + (size_t)O_SZ * H_SZ * 2;           // u64 [8][2][32][128] (512 KB)
constexpr size_t TAG_OFF  = HB_OFF   + (size_t)8 * 8192 * 8;              // u32 [8][32] (1 KB)

// ---------------- agent-scope (L3 coherence point) helpers — proven r2/r6/r8 ----------------
__device__ __forceinline__ u64 ag_load64(const u64* p) {
  return __hip_atomic_load(p, __ATOMIC_RELAXED, __HIP_MEMORY_SCOPE_AGENT);
}
__device__ __forceinline__ void ag_store64(u64* p, u64 v) {
  __hip_atomic_store(p, v, __ATOMIC_RELAXED, __HIP_MEMORY_SCOPE_AGENT);
}
__device__ __forceinline__ unsigned ag_load32(const unsigned* p) {
  return __hip_atomic_load(p, __ATOMIC_RELAXED, __HIP_MEMORY_SCOPE_AGENT);
}
__device__ __forceinline__ void ag_store32(unsigned* p, unsigned v) {
  __hip_atomic_store(p, v, __ATOMIC_RELAXED, __HIP_MEMORY_SCOPE_AGENT);
}

__device__ __forceinline__ float ftanh(float z) {
  // tanh(z) = 1 - 2/(e^{2z}+1); e^{2z} = 2^(2*log2e*z). Limits: +inf->1, -inf->-1.
  float e = __builtin_amdgcn_exp2f(z * 2.8853900817779268f);
  return fmaf(-2.f, __builtin_amdgcn_rcpf(e + 1.f), 1.f);
}

// ---------------- prep kernels (proven) ----------------
__global__ void k_cvt_x(const float* __restrict__ in, _Float16* __restrict__ out) {
  size_t i = ((size_t)blockIdx.x * 256 + threadIdx.x) * 8;
  float4 a = *(const float4*)(in + i);
  float4 b = *(const float4*)(in + i + 4);
  half8 h;
  h[0] = (_Float16)a.x; h[1] = (_Float16)a.y; h[2] = (_Float16)a.z; h[3] = (_Float16)a.w;
  h[4] = (_Float16)b.x; h[5] = (_Float16)b.y; h[6] = (_Float16)b.z; h[7] = (_Float16)b.w;
  *(half8*)(out + i) = h;
}

__global__ void k_transpose_cvt(const float* __restrict__ in, _Float16* __restrict__ out,
                                int K, int N) {
  int k = blockIdx.x * 256 + threadIdx.x;
  int n = blockIdx.y;
  out[(size_t)n * K + k] = (_Float16)in[(size_t)k * N + n];
}

// ---------------- phase 1: xW = x @ W_xh + b -> f16 [S][B][H] (proven) ----------------
__launch_bounds__(256, 1)
__global__ void k_xw_gemm(const _Float16* __restrict__ A,   // [65536][512]
                          const _Float16* __restrict__ BT,  // [1024][512]
                          const float* __restrict__ bias,   // [1024]
                          _Float16* __restrict__ xw)        // [S][B][H]
{
  const int m0 = blockIdx.y * 128;
  const int n0 = blockIdx.x * 128;
  __shared__ __align__(16) _Float16 la[128][72];
  __shared__ __align__(16) _Float16 lb[128][72];
  const int tid = threadIdx.x;
  const int w = tid >> 6, l = tid & 63;
  const int wr = w >> 1, wc = w & 1;
  const int cl = l & 15;
  const int kh = (l >> 4) << 3;
  const int rl = (l >> 4) << 2;

  f32x4 acc[4][4] = {};

  for (int kb = 0; kb < 512; kb += 64) {
    {
      const int r = tid >> 1, sg = tid & 1;
      const _Float16* ga = A  + (size_t)(m0 + r) * 512 + kb + sg * 32;
      const _Float16* gb = BT + (size_t)(n0 + r) * 512 + kb + sg * 32;
      _Float16* da = &la[r][sg * 32];
      _Float16* db = &lb[r][sg * 32];
      #pragma unroll
      for (int i = 0; i < 4; i++) *(half8*)(da + i * 8) = *(const half8*)(ga + i * 8);
      #pragma unroll
      for (int i = 0; i < 4; i++) *(half8*)(db + i * 8) = *(const half8*)(gb + i * 8);
    }
    __syncthreads();
    #pragma unroll
    for (int kk = 0; kk < 64; kk += 32) {
      half8 af[4], bf[4];
      #pragma unroll
      for (int mi = 0; mi < 4; mi++) af[mi] = *(const half8*)(&la[wr * 64 + mi * 16 + cl][kk + kh]);
      #pragma unroll
      for (int ni = 0; ni < 4; ni++) bf[ni] = *(const half8*)(&lb[wc * 64 + ni * 16 + cl][kk + kh]);
      #pragma unroll
      for (int mi = 0; mi < 4; mi++)
        #pragma unroll
        for (int ni = 0; ni < 4; ni++)
          acc[mi][ni] = MFMA16(af[mi], bf[ni], acc[mi][ni]);
    }
    __syncthreads();
  }

  #pragma unroll
  for (int mi = 0; mi < 4; mi++)
    #pragma unroll
    for (int ni = 0; ni < 4; ni++) {
      const int col = n0 + wc * 64 + ni * 16 + cl;
      const float bv = bias[col];
      #pragma unroll
      for (int r = 0; r < 4; r++) {
        const int m = m0 + wr * 64 + mi * 16 + rl + r;
        const int b = m >> 9;        // A rows are (b, s), S=512
        const int s = m & 511;
        xw[((size_t)(s * B_SZ + b) << 10) + col] = (_Float16)(acc[mi][ni][r] + bv);
      }
    }
}

// ---------------- phase 2+3: persistent recurrence ----------------
// 8 groups (g=bid&7, 16 batch rows) x 16 wgs (j=bid>>3), 2 waves/wg.
// Each WAVE is an independent producer/consumer slot p = j*2+w owning 32 H-cols;
// NO intra-step __syncthreads. W^T rows 64j..64j+63 live in LDS (129 KB).
// h block p (16 rows x 32 cols) lives in hb as 128 u64 in MFMA-A-fragment order:
//   u64 idx = p*128 + row*8 + colquad  (colquad = col/4).
//   producer lane l writes row=l>>2, quads (l&3)*2+{0,1}.
//   consumer lane l reads row=l&15, quads (l>>4)*2+{0,1}  (8 f16 = A-frag).
// Protocol (all proven classes): plain agent stores -> vmcnt(0) drain ->
// per-wave tag store; consumer polls all 32 tags (1 load/lane, 1 cacheline)
// then bulk-loads h via compiler-pipelined issueq/mfmaq ping-pong (r8 pattern).
// WAR (2 parity buffers): tag_p = t implies wave p finished READING h_{t-1},
// so overwriting h_{t-1}'s parity at step t is safe (induction as r6/r7).
// Replay-safe: tags memset to 0 each launch. Polls bounded -> no hang possible.

__device__ __forceinline__ void poll_tags(const unsigned* gtag, int l, unsigned t) {
  for (int it = 0; it < (1 << 17); ++it) {
    unsigned tg = ag_load32(gtag + (l & 31));
    if (__all((int)(tg >= t))) break;
    __builtin_amdgcn_s_sleep(1);
  }
  __builtin_amdgcn_sched_barrier(0);   // keep h loads below the poll
}

template<int BLK0>
__device__ __forceinline__ void issueq8(u64 (&buf)[8][2], const u64* hrow) {
  #pragma unroll
  for (int b = 0; b < 8; b++) {
    buf[b][0] = ag_load64(hrow + ((BLK0 + b) << 7));
    buf[b][1] = ag_load64(hrow + ((BLK0 + b) << 7) + 1);
  }
}

template<int BLK0>
__device__ __forceinline__ void mfmaq8(const u64 (&buf)[8][2],
                                       const _Float16 (*lw)[1032],
                                       int w, int cl, int kh, f32x4 (&acc)[2][2]) {
  #pragma unroll
  for (int b = 0; b < 8; b++) {
    const int p = BLK0 + b;
    u64x2 w2 = { buf[b][0], buf[b][1] };
    half8 a = __builtin_bit_cast(half8, w2);
    half8 b0 = *(const half8*)&lw[(w << 5) + cl][(p << 5) + kh];
    half8 b1 = *(const half8*)&lw[(w << 5) + 16 + cl][(p << 5) + kh];
    acc[0][p & 1] = MFMA16(a, b0, acc[0][p & 1]);
    acc[1][p & 1] = MFMA16(a, b1, acc[1][p & 1]);
  }
}

template<int BLK0>
__device__ __forceinline__ void mfmaq_o8(const u64 (&buf)[8][2],
                                         const _Float16* bsrc,
                                         int kh, f32x4 (&oa)[2]) {
  #pragma unroll
  for (int b = 0; b < 8; b++) {
    const int p = BLK0 + b;
    u64x2 w2 = { buf[b][0], buf[b][1] };
    half8 a = __builtin_bit_cast(half8, w2);
    half8 bv = *(const half8*)(bsrc + (p << 5) + kh);
    oa[p & 1] = MFMA16(a, bv, oa[p & 1]);
  }
}

__launch_bounds__(128, 1)
__global__ void k_rnn(const _Float16* __restrict__ xw,    // [S][B][H]
                      const _Float16* __restrict__ WhhT,  // [H][H]
                      const _Float16* __restrict__ WyhT,  // [O][H]
                      const float* __restrict__ Wby,
                      u64* __restrict__ hb,               // [8][2][32][128]
                      unsigned* __restrict__ tags,        // [8][32]
                      float* __restrict__ out)            // [B][O]
{
  __shared__ __align__(16) _Float16 lw[64][1032];   // W_hh^T slice (129 KB)
  __shared__ __align__(16) _Float16 stb[2][16][40]; // per-wave bounce (80B rows)

  const int bid = blockIdx.x;
  const int g = bid & 7, j = bid >> 3;     // j in 0..15
  const int tid = threadIdx.x;
  const int w = tid >> 6, l = tid & 63;
  const int p_self = (j << 1) | w;         // slot 0..31
  const int cl  = l & 15;
  const int kh  = (l >> 4) << 3;           // f16 offset in 32-col block
  const int kh2 = (l >> 4) << 1;           // u64 quad offset = kh/4
  const int rl  = (l >> 4) << 2;
  const int r0  = g << 4;
  const int colbase = p_self << 5;
  unsigned* gtag = tags + (g << 5);
  u64* hbg = hb + ((size_t)g << 13);       // 8192 u64 per group

  // load W_hh^T rows 64j..64j+63 into LDS (once)
  for (int i = tid; i < 64 * 128; i += 128) {
    const int row = i >> 7, c8 = (i & 127) << 3;
    *(half8*)&lw[row][c8] = *(const half8*)&WhhT[((size_t)((j << 6) + row) << 10) + c8];
  }
  __syncthreads();   // only barrier outside the loop prologue

  for (int t = 0; t < 512; t++) {
    // xw_t addend for this wave's 16x32 block (plain HBM loads, overlap the poll)
    float xv[2][4];
    {
      const _Float16* p = xw + ((size_t)(t * 128 + r0 + rl) << 10) + colbase + cl;
      #pragma unroll
      for (int f = 0; f < 2; f++)
        #pragma unroll
        for (int r = 0; r < 4; r++)
          xv[f][r] = (float)p[((size_t)r << 10) + (f << 4)];
    }

    f32x4 acc[2][2] = {{{}, {}}, {{}, {}}};
    if (t > 0) {
      poll_tags(gtag, l, (unsigned)t);
      const u64* hrow = hbg + ((size_t)(t & 1) << 12) + (cl << 3) + kh2;
      u64 qa[8][2], qb[8][2];
      issueq8<0>(qa, hrow);
      issueq8<8>(qb, hrow);
      mfmaq8<0>(qa, lw, w, cl, kh, acc);    // compiler waits qa, qb stays in flight
      issueq8<16>(qa, hrow);
      mfmaq8<8>(qb, lw, w, cl, kh, acc);
      issueq8<24>(qb, hrow);
      mfmaq8<16>(qa, lw, w, cl, kh, acc);
      mfmaq8<24>(qb, lw, w, cl, kh, acc);
    }

    // h_{t+1} = tanh(xw_t + h_t @ W_hh): wave-local bounce, fragment-order publish
    #pragma unroll
    for (int f = 0; f < 2; f++)
      #pragma unroll
      for (int r = 0; r < 4; r++) {
        float z = xv[f][r] + acc[f][0][r] + acc[f][1][r];
        stb[w][rl + r][(f << 4) + cl] = (_Float16)ftanh(z);
      }
    asm volatile("s_waitcnt lgkmcnt(0)" ::: "memory");   // wave-local LDS RAW
    __builtin_amdgcn_sched_barrier(0);
    {
      const u64* sp = (const u64*)&stb[w][l >> 2][(l & 3) << 3];
      u64 p0 = sp[0], p1 = sp[1];
      u64* dst = hbg + ((size_t)((t + 1) & 1) << 12) + (p_self << 7)
               + ((l >> 2) << 3) + ((l & 3) << 1);
      ag_store64(dst, p0);
      ag_store64(dst + 1, p1);
    }
    asm volatile("s_waitcnt vmcnt(0)" ::: "memory");     // h at coherence point
    if (l == 0) ag_store32(gtag + p_self, (unsigned)(t + 1));
  }

  // ---------- phase 3: out = h_512 @ W_yh + b_y (h_512 in parity-0) ----------
  poll_tags(gtag, l, 512u);
  {
    const u64* hrow = hbg + (cl << 3) + kh2;
    const int oc = (p_self << 4) + cl;          // 32 slots x 16 cols = 512
    const _Float16* bsrc = WyhT + ((size_t)oc << 10);
    f32x4 oa[2] = {{}, {}};
    u64 qa[8][2], qb[8][2];
    issueq8<0>(qa, hrow);
    issueq8<8>(qb, hrow);
    mfmaq_o8<0>(qa, bsrc, kh, oa);
    issueq8<16>(qa, hrow);
    mfmaq_o8<8>(qb, bsrc, kh, oa);
    issueq8<24>(qb, hrow);
    mfmaq_o8<16>(qa, bsrc, kh, oa);
    mfmaq_o8<24>(qb, bsrc, kh, oa);

    const float bb = Wby[oc];
    #pragma unroll
    for (int r = 0; r < 4; r++)
      out[((size_t)(r0 + rl + r) << 9) + oc] = oa[0][r] + oa[1][r] + bb;
  }
}

// ---------------- host ----------------
extern "C" void kernel_launch(void* const* d_in, const int* in_sizes, int n_in,
                              void* d_out, int out_size, void* d_ws, size_t ws_size,
                              hipStream_t stream) {
  const float* x   = (const float*)d_in[0];
  const float* Wxh = (const float*)d_in[1];
  const float* Whh = (const float*)d_in[2];
  const float* Wyh = (const float*)d_in[3];
  const float* Wbh = (const float*)d_in[4];
  const float* Wby = (const float*)d_in[5];
  float* out = (float*)d_out;

  char* ws = (char*)d_ws;
  _Float16* xw   = (_Float16*)(ws + XW_OFF);
  _Float16* x16  = (_Float16*)(ws + X16_OFF);
  _Float16* WxhT = (_Float16*)(ws + WXHT_OFF);
  _Float16* WhhT = (_Float16*)(ws + WHHT_OFF);
  _Float16* WyhT = (_Float16*)(ws + WYHT_OFF);
  u64*      hb   = (u64*)(ws + HB_OFF);
  unsigned* tags = (unsigned*)(ws + TAG_OFF);

  hipMemsetAsync(tags, 0, 8 * 32 * sizeof(unsigned), stream);

  k_cvt_x<<<16384, 256, 0, stream>>>(x, x16);
  k_transpose_cvt<<<dim3(2, 1024), 256, 0, stream>>>(Wxh, WxhT, 512, 1024);
  k_transpose_cvt<<<dim3(4, 1024), 256, 0, stream>>>(Whh, WhhT, 1024, 1024);
  k_transpose_cvt<<<dim3(4, 512),  256, 0, stream>>>(Wyh, WyhT, 1024, 512);

  k_xw_gemm<<<dim3(8, 512), 256, 0, stream>>>(x16, WxhT, Wbh, xw);

  k_rnn<<<128, 128, 0, stream>>>(xw, WhhT, WyhT, Wby, hb, tags, out);
}